// Round 9
// baseline (1993.232 us; speedup 1.0000x reference)
//
#include <hip/hip_runtime.h>
#include <stdint.h>

typedef _Float16 half8 __attribute__((ext_vector_type(8)));
typedef float f32x4 __attribute__((ext_vector_type(4)));

#define MARGIN 1.5e-2f

// ---- out element offsets (flattened tuple, return order) ----
#define O_STE_HR1 0
#define O_STE_LR1 8388608
#define O_STE_HR2 16777216
#define O_STE_LR2 25165824
#define O_DIFF    33554432
#define O_IND_HR1 33554436
#define O_IND_LR1 33587204
#define O_IND_HR2 33619972
#define O_IND_LR2 33652740
#define O_DIST_HR1 33685508
#define O_DIST_LR1 67239940
#define O_DIST_HR2 100794372
#define O_DIST_LR2 134348804

// ---- ws byte offsets ----
#define W_DIFF 0          // 2 x double
#define W_CNT  16         // u32 flagged count
#define W_SSE  4096       // f32[1024] sumsq_e (approx path)
#define W_EF16 8192       // _Float16 [1024 cols][256 k]  (512 KB)
#define W_ET   532480     // f32 [1024 cols][256 k]       (1 MB) exact transpose
#define W_SUM_MIN1 1581056   // f32 [8][65536]
#define W_SUM_MIN2 3678208   // f32 [8][65536]
#define W_SUM_K    5775360   // u32 [8][65536]
#define W_FIND     7872512   // i32 [65536] final index
#define W_FROWS    8134656   // i32 [65536] flagged rows
#define W_FMIN     8396800   // f32 [65536] flagged row min1
#define W_T1       8658944   // f32 [65536] numpy-exact sum(x^2) per row
#define W_T3       8921088   // f32 [1024]  numpy-exact sum(e^2) per col

__device__ __forceinline__ void ins2(unsigned long long k, unsigned long long &a, unsigned long long &b){
  if (k < a){ b = a; a = k; } else if (k < b){ b = k; }
}

// ---------- prep: transpose embed -> Et (f32), Ef16 (f16), sumsq_e (approx) ----------
__global__ __launch_bounds__(256) void prep(const float* __restrict__ e, char* __restrict__ ws){
  __shared__ float tile[64][65];
  int t = threadIdx.x;
  int k0 = (blockIdx.x & 3) * 64;
  int c0 = (blockIdx.x >> 2) * 64;
  float* Et = (float*)(ws + W_ET);
  _Float16* Ef = (_Float16*)(ws + W_EF16);
  float* sse = (float*)(ws + W_SSE);
#pragma unroll
  for (int p = 0; p < 4; p++){
    int kr = p*16 + (t >> 4);
    int cc = (t & 15) * 4;
    float4 v = *(const float4*)(e + (k0 + kr)*1024 + c0 + cc);
    tile[kr][cc+0]=v.x; tile[kr][cc+1]=v.y; tile[kr][cc+2]=v.z; tile[kr][cc+3]=v.w;
  }
  __syncthreads();
#pragma unroll
  for (int p = 0; p < 4; p++){
    int cr = p*16 + (t >> 4);
    int kc = (t & 15) * 4;
    float4 v;
    v.x = tile[kc+0][cr]; v.y = tile[kc+1][cr]; v.z = tile[kc+2][cr]; v.w = tile[kc+3][cr];
    *(float4*)(Et + (c0+cr)*256 + k0 + kc) = v;
    union { _Float16 h[4]; unsigned long long u; } pk;
    pk.h[0]=(_Float16)v.x; pk.h[1]=(_Float16)v.y; pk.h[2]=(_Float16)v.z; pk.h[3]=(_Float16)v.w;
    *(unsigned long long*)(Ef + (c0+cr)*256 + k0 + kc) = pk.u;
  }
  if (t < 64){
    float s = 0.f;
    for (int k = 0; k < 64; k++){ float v = tile[k][t]; s += v*v; }
    atomicAdd(&sse[c0 + t], s);
  }
}

// ---------- Xf16: RTE f32->f16 image of both inputs, staged in dist2 region ----------
__global__ __launch_bounds__(256) void xf16_prep(const float* __restrict__ xhr, const float* __restrict__ xlr,
                                                 float* __restrict__ out){
  _Float16* dst = (_Float16*)(out + O_DIST_HR2);
  size_t i = (size_t)blockIdx.x*256 + threadIdx.x;   // float4 index
#pragma unroll
  for (int h = 0; h < 2; h++){
    const float4* X = (const float4*)(h ? xlr : xhr);
    _Float16* D = dst + (size_t)h*8388608;
#pragma unroll
    for (int k = 0; k < 4; k++){
      size_t f4 = (size_t)k*524288 + i;
      float4 v = X[f4];
      union { _Float16 h4[4]; unsigned long long u; } pk;
      pk.h4[0]=(_Float16)v.x; pk.h4[1]=(_Float16)v.y; pk.h4[2]=(_Float16)v.z; pk.h4[3]=(_Float16)v.w;
      *(unsigned long long*)(D + f4*4) = pk.u;
    }
  }
}

// ---------- numpy-exact T1[r] = (x_r**2).sum() (AVX512 twin) ----------
__global__ __launch_bounds__(256) void t1_np(const float* __restrict__ xhr, const float* __restrict__ xlr,
                                             char* __restrict__ ws){
  __shared__ float rowbuf[64][260];
  int b = blockIdx.x;
  int h = b >> 9;
  int r0 = (b & 511) * 64;
  const float* X = h ? xlr : xhr;
  int t = threadIdx.x;
#pragma unroll
  for (int p = 0; p < 16; p++){
    int idx = p*256 + t;
    int rr = idx >> 6, cc = idx & 63;
    float4 v = *(const float4*)(X + (size_t)(r0+rr)*256 + cc*4);
    rowbuf[rr][cc*4+0]=v.x; rowbuf[rr][cc*4+1]=v.y; rowbuf[rr][cc*4+2]=v.z; rowbuf[rr][cc*4+3]=v.w;
  }
  __syncthreads();
  if (t < 64){
    const float* a = &rowbuf[t][0];
    float blk[2];
#pragma unroll
    for (int p = 0; p < 2; p++){
      const float* ap = a + p*128;
      float s[16];
#pragma unroll
      for (int l = 0; l < 16; l++){
        float q0 = __fmul_rn(ap[l      ], ap[l      ]);
        float q1 = __fmul_rn(ap[l + 16 ], ap[l + 16 ]);
        float q2 = __fmul_rn(ap[l + 32 ], ap[l + 32 ]);
        float q3 = __fmul_rn(ap[l + 48 ], ap[l + 48 ]);
        float q4 = __fmul_rn(ap[l + 64 ], ap[l + 64 ]);
        float q5 = __fmul_rn(ap[l + 80 ], ap[l + 80 ]);
        float q6 = __fmul_rn(ap[l + 96 ], ap[l + 96 ]);
        float q7 = __fmul_rn(ap[l + 112], ap[l + 112]);
        s[l] = __fadd_rn(__fadd_rn(__fadd_rn(q0,q1), __fadd_rn(q2,q3)),
                         __fadd_rn(__fadd_rn(q4,q5), __fadd_rn(q6,q7)));
      }
      float u[8];
#pragma unroll
      for (int l = 0; l < 8; l++) u[l] = __fadd_rn(s[l], s[l+8]);
      float v[4];
#pragma unroll
      for (int l = 0; l < 4; l++) v[l] = __fadd_rn(u[l], u[l+4]);
      blk[p] = __fadd_rn(__fadd_rn(v[0], v[2]), __fadd_rn(v[1], v[3]));
    }
    ((float*)(ws + W_T1))[h*32768 + r0 + t] = __fadd_rn(blk[0], blk[1]);
  }
}

// ---------- numpy-exact T3[k] = (e**2).sum(0): strictly sequential ----------
__global__ __launch_bounds__(256) void t3_np(const float* __restrict__ e, char* __restrict__ ws){
  int k = blockIdx.x*256 + threadIdx.x;
  float v0 = e[k];
  float acc = __fmul_rn(v0, v0);
  for (int i = 1; i < 256; i++){
    float v = e[i*1024 + k];
    acc = __fadd_rn(acc, __fmul_rn(v, v));
  }
  ((float*)(ws + W_T3))[k] = acc;
}

// ---------- main GEMM: r5/r7 structure; dist emitted as f16 into the ste region (staging).
// Exact f32 d drives top-2/flags; staging is stream-written via a swizzled f16 LDS tile. ----------
__global__ __launch_bounds__(512, 4) void gemm_dist(char* __restrict__ ws, float* __restrict__ out){
  // Bimg/f16-dtile [0,65536) | sx f32[256] | se f32[128] | t2 u64[256][4]
  __shared__ __align__(16) char smem[75264];
  _Float16* Bimg = (_Float16*)smem;
  float* sx = (float*)(smem + 65536);
  float* se = (float*)(smem + 66560);
  unsigned long long* t2 = (unsigned long long*)(smem + 67072);

  int bid = blockIdx.x;
  int xcd = bid & 7, slot = bid >> 3;
  int ct = slot & 7;
  int panel = ((slot >> 3) << 3) + xcd;
  int lrow0 = (panel & 127) << 8;
  int col0 = ct << 7;
  int t = threadIdx.x, lane = t & 63, wid = t >> 6;
  int wm = wid >> 1, wn = wid & 1;
  int kg = lane >> 4, rl = lane & 15;

  const _Float16* Xf = (const _Float16*)(out + O_DIST_HR2)
                     + ((panel < 128) ? 0 : 8388608) + (size_t)lrow0*256;

  // --- B image staging (f16, 16B-unit XOR swizzle) ---
  const _Float16* Ef = (const _Float16*)(ws + W_EF16);
#pragma unroll
  for (int i = 0; i < 8; i++){
    int chunk = i*512 + t;
    int c = chunk >> 5, kc = chunk & 31;
    uint4 v = *(const uint4*)(Ef + (size_t)(col0 + c)*256 + kc*8);
    int off = c*512 + ((kc*16) ^ ((c & 7) << 4));
    *(uint4*)((char*)Bimg + off) = v;
  }
  if (t < 128) se[t] = ((const float*)(ws + W_SSE))[col0 + t];
  if (t < 256) sx[t] = ((const float*)(ws + W_T1))[((panel < 128) ? 0 : 32768) + lrow0 + t];
  __syncthreads();

  f32x4 acc[4][4] = {};
#pragma unroll 2
  for (int kk = 0; kk < 8; kk++){
    half8 av[4], bv[4];
#pragma unroll
    for (int fm = 0; fm < 4; fm++){
      int row = wm*64 + fm*16 + rl;
      av[fm] = *(const half8*)(Xf + (size_t)row*256 + kk*32 + kg*8);
    }
#pragma unroll
    for (int fn = 0; fn < 4; fn++){
      int col = wn*64 + fn*16 + rl;
      bv[fn] = *(const half8*)((char*)Bimg + col*512 + ((kk*64 + kg*16) ^ ((col & 7) << 4)));
    }
#pragma unroll
    for (int fm = 0; fm < 4; fm++)
#pragma unroll
      for (int fn = 0; fn < 4; fn++)
        acc[fm][fn] = __builtin_amdgcn_mfma_f32_16x16x32_f16(av[fm], bv[fn], acc[fm][fn], 0, 0, 0);
  }
  __syncthreads();    // Bimg reads done; f16 tile overwrite safe

  // --- top2 (exact f32 d, same order as r5/r7) + f16 tile fill ---
  for (int fm = 0; fm < 4; fm++){
    unsigned long long ta[4], tb[4];
#pragma unroll
    for (int j = 0; j < 4; j++){ ta[j] = ~0ull; tb[j] = ~0ull; }
#pragma unroll
    for (int fn = 0; fn < 4; fn++){
      int col = wn*64 + fn*16 + rl;
      float sec = se[col];
      int gcol = col0 + col;
      f32x4 a = acc[fm][fn];
#pragma unroll
      for (int j = 0; j < 4; j++){
        int br = wm*64 + fm*16 + kg*4 + j;       // C/D layout: col=lane&15, row=(lane>>4)*4+reg
        float d = fmaf(-2.f, a[j], sx[br] + sec);
        *(_Float16*)(smem + br*256 + ((col*2) ^ ((br & 7) << 4))) = (_Float16)d;
        unsigned long long key = ((unsigned long long)__float_as_uint(d) << 32) | (unsigned)gcol;
        ins2(key, ta[j], tb[j]);
      }
    }
#pragma unroll
    for (int m = 1; m < 16; m <<= 1){
#pragma unroll
      for (int j = 0; j < 4; j++){
        unsigned long long oa = __shfl_xor(ta[j], m);
        unsigned long long ob = __shfl_xor(tb[j], m);
        ins2(oa, ta[j], tb[j]); ins2(ob, ta[j], tb[j]);
      }
    }
    if (rl == 0){
#pragma unroll
      for (int j = 0; j < 4; j++){
        int br = wm*64 + fm*16 + kg*4 + j;
        t2[br*4 + wn*2 + 0] = ta[j];
        t2[br*4 + wn*2 + 1] = tb[j];
      }
    }
  }
  __syncthreads();

  // --- stream f16 tile (256 rows x 256B) to staging (ste region), 8B/lane nt ---
  size_t growbase = (size_t)(((panel < 128) ? 0 : 32768) + lrow0);
  char* stg = (char*)out;
#pragma unroll
  for (int it = 0; it < 16; it++){
    int idx = it*512 + t;
    int row = idx >> 5, c8 = idx & 31;
    unsigned long long v = *(const unsigned long long*)(smem + row*256 + ((c8*8) ^ ((row & 7) << 4)));
    __builtin_nontemporal_store(v,
      (unsigned long long*)(stg + (growbase + row)*2048 + col0*2 + c8*8));
  }

  if (t < 256){
    unsigned long long a = t2[t*4+0], b = t2[t*4+1];
    ins2(t2[t*4+2], a, b);
    ins2(t2[t*4+3], a, b);
    int rc = panel*256 + t;
    ((float*)(ws + W_SUM_MIN1))[ct*65536 + rc] = __uint_as_float((unsigned)(a >> 32));
    ((float*)(ws + W_SUM_MIN2))[ct*65536 + rc] = __uint_as_float((unsigned)(b >> 32));
    ((unsigned*)(ws + W_SUM_K))[ct*65536 + rc] = (unsigned)a;
  }
}

// ---------- expand: f16 staging -> f32 dist1 + dist2 (clean streaming writer) ----------
__global__ __launch_bounds__(256) void expand_dist(float* __restrict__ out){
  const unsigned long long* src = (const unsigned long long*)out;   // staging: 4 f16 per u64
  float* d1 = out + O_DIST_HR1;
  float* d2 = out + O_DIST_HR2;
  size_t i = (size_t)blockIdx.x*256 + threadIdx.x;
#pragma unroll
  for (int k = 0; k < 32; k++){
    size_t idx = (size_t)k*524288 + i;        // 16.78M u64 = 67.1M f16
    union { unsigned long long u; _Float16 h[4]; } pk;
    pk.u = src[idx];
    f32x4 q;
    q[0] = (float)pk.h[0]; q[1] = (float)pk.h[1]; q[2] = (float)pk.h[2]; q[3] = (float)pk.h[3];
    __builtin_nontemporal_store(q, (f32x4*)(d1 + idx*4));
    __builtin_nontemporal_store(q, (f32x4*)(d2 + idx*4));
  }
}

// ---------- merge per-tile top2 -> global top2, flag narrow-gap rows ----------
__global__ __launch_bounds__(256) void merge_flag(char* __restrict__ ws){
  int rc = blockIdx.x*256 + threadIdx.x;
  const float* m1 = (const float*)(ws + W_SUM_MIN1);
  const float* m2 = (const float*)(ws + W_SUM_MIN2);
  const unsigned* kk = (const unsigned*)(ws + W_SUM_K);
  unsigned long long a = ~0ull, b = ~0ull;
#pragma unroll
  for (int ctt = 0; ctt < 8; ctt++){
    int i = ctt*65536 + rc;
    unsigned long long ka = ((unsigned long long)__float_as_uint(m1[i]) << 32) | kk[i];
    unsigned long long kb = ((unsigned long long)__float_as_uint(m2[i]) << 32) | 0xffffffffu;
    ins2(ka, a, b); ins2(kb, a, b);
  }
  ((int*)(ws + W_FIND))[rc] = (int)(unsigned)a;
  float f1 = __uint_as_float((unsigned)(a >> 32));
  float f2 = __uint_as_float((unsigned)(b >> 32));
  if (f2 - f1 < MARGIN){
    unsigned idx = atomicAdd((unsigned*)(ws + W_CNT), 1u);
    ((int*)(ws + W_FROWS))[idx] = rc;
    ((float*)(ws + W_FMIN))[idx] = f1;
  }
}

// ---------- numpy-f32-exact re-decision for flagged rows (scans f16 staging).
// myk[16]: 16 x 64 lanes = 1024 = whole codebook -> candidate drop impossible. ----------
__global__ __launch_bounds__(256) void refine_np(const float* __restrict__ xhr, const float* __restrict__ xlr,
                                                 char* __restrict__ ws, const float* __restrict__ out){
  unsigned nf = *(const unsigned*)(ws + W_CNT);
  int lane = threadIdx.x & 63;
  unsigned wgl = blockIdx.x*4 + (threadIdx.x >> 6);
  const float* Et = (const float*)(ws + W_ET);
  const float* T1 = (const float*)(ws + W_T1);
  const float* T3 = (const float*)(ws + W_T3);
  const int* rows = (const int*)(ws + W_FROWS);
  const float* fmn = (const float*)(ws + W_FMIN);
  int* find = (int*)(ws + W_FIND);
  for (unsigned ii = wgl; ii < nf; ii += gridDim.x*4){
    int rc = rows[ii];
    float thr = fmn[ii] + MARGIN + 0.15f;   // f16 ulp(256)=0.25 -> round err 0.125, + 2x GEMM err
    int h = rc >> 15, r = rc & 32767;
    const float* X = h ? xlr : xhr;
    const float* xrow = X + (size_t)r*256;
    const _Float16* drow = (const _Float16*)out + (size_t)(h*32768 + r)*1024;
    float t1v = T1[rc];
    int myk[16]; int mycnt = 0; int cnt = 0;
    for (int j = 0; j < 16; j++){
      float dv = (float)drow[j*64 + lane];
      unsigned long long m = __ballot(dv <= thr);
      while (m){
        int src = __ffsll((unsigned long long)m) - 1;
        m &= m - 1;
        if ((cnt & 63) == lane && mycnt < 16) myk[mycnt++] = j*64 + src;
        cnt++;
      }
    }
    unsigned long long bestkey = ~0ull;
    for (int b = 0; b < mycnt; b++){
      int k = myk[b];
      const float4* e4 = (const float4*)(Et + (size_t)k*256);
      const float4* x4 = (const float4*)xrow;
      float c = 0.f;
      for (int i = 0; i < 64; i++){
        float4 xv = x4[i], ev = e4[i];
        c = fmaf(xv.x, ev.x, c);
        c = fmaf(xv.y, ev.y, c);
        c = fmaf(xv.z, ev.z, c);
        c = fmaf(xv.w, ev.w, c);
      }
      float d = __fadd_rn(__fsub_rn(t1v, __fmul_rn(2.f, c)), T3[k]);
      unsigned long long key = ((unsigned long long)__float_as_uint(d) << 32) | (unsigned)k;
      if (key < bestkey) bestkey = key;
    }
#pragma unroll
    for (int m2 = 1; m2 < 64; m2 <<= 1){
      unsigned long long o = __shfl_xor(bestkey, m2);
      if (o < bestkey) bestkey = o;
    }
    if (lane == 0) find[rc] = (int)(unsigned)(bestkey & 0xffffffffu);
  }
}

// ---------- gather q, write ste x2 + ind x2, accumulate diff ----------
__global__ __launch_bounds__(256) void finalize(const float* __restrict__ xhr, const float* __restrict__ xlr,
                                                char* __restrict__ ws, float* __restrict__ out){
  int b = blockIdx.x;
  int h = b >> 9, chunk = b & 511;
  const float* X = h ? xlr : xhr;
  int wid = threadIdx.x >> 6, lane = threadIdx.x & 63;
  const float* Et = (const float*)(ws + W_ET);
  const int* find = (const int*)(ws + W_FIND);
  int sb1 = h ? O_STE_LR1 : O_STE_HR1;
  int sb2 = h ? O_STE_LR2 : O_STE_HR2;
  int ib1 = h ? O_IND_LR1 : O_IND_HR1;
  int ib2 = h ? O_IND_LR2 : O_IND_HR2;
  double part = 0.0;
  for (int rr = wid; rr < 64; rr += 4){
    int r = chunk*64 + rr;
    int k = find[h*32768 + r];
    float4 q = *(const float4*)(Et + (size_t)k*256 + lane*4);
    float4 x = *(const float4*)(X + (size_t)r*256 + lane*4);
    *(float4*)(out + sb1 + r*256 + lane*4) = q;
    *(float4*)(out + sb2 + r*256 + lane*4) = q;
    if (lane == 0){ out[ib1 + r] = (float)k; out[ib2 + r] = (float)k; }
    double d0 = (double)q.x - x.x, d1 = (double)q.y - x.y;
    double d2 = (double)q.z - x.z, d3 = (double)q.w - x.w;
    part += d0*d0 + d1*d1 + d2*d2 + d3*d3;
  }
#pragma unroll
  for (int m = 1; m < 64; m <<= 1) part += __shfl_xor(part, m);
  __shared__ double wsum[4];
  if (lane == 0) wsum[wid] = part;
  __syncthreads();
  if (threadIdx.x == 0)
    atomicAdd((double*)(ws + W_DIFF) + h, wsum[0] + wsum[1] + wsum[2] + wsum[3]);
}

__global__ void fin_diff(const char* __restrict__ ws, float* __restrict__ out){
  if (threadIdx.x == 0 && blockIdx.x == 0){
    const double* d = (const double*)(ws + W_DIFF);
    float dh = (float)(d[0] / 8388608.0);
    float dl = (float)(d[1] / 8388608.0);
    out[O_DIFF+0] = dh; out[O_DIFF+1] = dl; out[O_DIFF+2] = dh; out[O_DIFF+3] = dl;
  }
}

extern "C" void kernel_launch(void* const* d_in, const int* in_sizes, int n_in,
                              void* d_out, int out_size, void* d_ws, size_t ws_size,
                              hipStream_t stream){
  const float* xhr = (const float*)d_in[0];
  const float* xlr = (const float*)d_in[1];
  const float* emb = (const float*)d_in[2];
  float* out = (float*)d_out;
  char* ws = (char*)d_ws;
  hipMemsetAsync(d_ws, 0, 8192, stream);
  prep<<<64, 256, 0, stream>>>(emb, ws);
  xf16_prep<<<2048, 256, 0, stream>>>(xhr, xlr, out);
  t1_np<<<1024, 256, 0, stream>>>(xhr, xlr, ws);
  t3_np<<<4, 256, 0, stream>>>(emb, ws);
  gemm_dist<<<2048, 512, 0, stream>>>(ws, out);
  merge_flag<<<256, 256, 0, stream>>>(ws);
  refine_np<<<1024, 256, 0, stream>>>(xhr, xlr, ws, out);
  expand_dist<<<2048, 256, 0, stream>>>(out);
  finalize<<<1024, 256, 0, stream>>>(xhr, xlr, ws, out);
  fin_diff<<<1, 64, 0, stream>>>(ws, out);
}

// Round 10
// 1587.779 us; speedup vs baseline: 1.2554x; 1.2554x over previous
//
#include <hip/hip_runtime.h>
#include <stdint.h>

typedef _Float16 half8 __attribute__((ext_vector_type(8)));
typedef float f32x4 __attribute__((ext_vector_type(4)));

#define MARGIN 1.5e-2f

// ---- out element offsets (flattened tuple, return order) ----
#define O_STE_HR1 0
#define O_STE_LR1 8388608
#define O_STE_HR2 16777216
#define O_STE_LR2 25165824
#define O_DIFF    33554432
#define O_IND_HR1 33554436
#define O_IND_LR1 33587204
#define O_IND_HR2 33619972
#define O_IND_LR2 33652740
#define O_DIST_HR1 33685508
#define O_DIST_LR1 67239940
#define O_DIST_HR2 100794372
#define O_DIST_LR2 134348804

// key/cnt planes live in the dist1 region until expand_dist overwrites it
#define CNT_U32_OFF 4194304   // u32 offset past 2,097,152 u64 keys

// ---- ws byte offsets ----
#define W_DIFF 0          // 2 x double
#define W_CNT  16         // u32 flagged count
#define W_SSE  4096       // f32[1024] sumsq_e (approx path)
#define W_EF16 8192       // _Float16 [1024 cols][256 k]  (512 KB)
#define W_ET   532480     // f32 [1024 cols][256 k]       (1 MB) exact transpose
#define W_FIND     7872512   // i32 [65536] final index
#define W_FROWS    8134656   // i32 [65536] flagged rows (bit31 = overflow)
#define W_FMIN     8396800   // f32 [65536] flagged row f1
#define W_T1       8658944   // f32 [65536] numpy-exact sum(x^2) per row
#define W_T3       8921088   // f32 [1024]  numpy-exact sum(e^2) per col

__device__ __forceinline__ void ins2(unsigned long long k, unsigned long long &a, unsigned long long &b){
  if (k < a){ b = a; a = k; } else if (k < b){ b = k; }
}

// ---------- prep: transpose embed -> Et (f32), Ef16 (f16), sumsq_e (approx) ----------
__global__ __launch_bounds__(256) void prep(const float* __restrict__ e, char* __restrict__ ws){
  __shared__ float tile[64][65];
  int t = threadIdx.x;
  int k0 = (blockIdx.x & 3) * 64;
  int c0 = (blockIdx.x >> 2) * 64;
  float* Et = (float*)(ws + W_ET);
  _Float16* Ef = (_Float16*)(ws + W_EF16);
  float* sse = (float*)(ws + W_SSE);
#pragma unroll
  for (int p = 0; p < 4; p++){
    int kr = p*16 + (t >> 4);
    int cc = (t & 15) * 4;
    float4 v = *(const float4*)(e + (k0 + kr)*1024 + c0 + cc);
    tile[kr][cc+0]=v.x; tile[kr][cc+1]=v.y; tile[kr][cc+2]=v.z; tile[kr][cc+3]=v.w;
  }
  __syncthreads();
#pragma unroll
  for (int p = 0; p < 4; p++){
    int cr = p*16 + (t >> 4);
    int kc = (t & 15) * 4;
    float4 v;
    v.x = tile[kc+0][cr]; v.y = tile[kc+1][cr]; v.z = tile[kc+2][cr]; v.w = tile[kc+3][cr];
    *(float4*)(Et + (c0+cr)*256 + k0 + kc) = v;
    union { _Float16 h[4]; unsigned long long u; } pk;
    pk.h[0]=(_Float16)v.x; pk.h[1]=(_Float16)v.y; pk.h[2]=(_Float16)v.z; pk.h[3]=(_Float16)v.w;
    *(unsigned long long*)(Ef + (c0+cr)*256 + k0 + kc) = pk.u;
  }
  if (t < 64){
    float s = 0.f;
    for (int k = 0; k < 64; k++){ float v = tile[k][t]; s += v*v; }
    atomicAdd(&sse[c0 + t], s);
  }
}

// ---------- Xf16: RTE f32->f16 image of both inputs, staged in dist2 region ----------
__global__ __launch_bounds__(256) void xf16_prep(const float* __restrict__ xhr, const float* __restrict__ xlr,
                                                 float* __restrict__ out){
  _Float16* dst = (_Float16*)(out + O_DIST_HR2);
  size_t i = (size_t)blockIdx.x*256 + threadIdx.x;   // float4 index
#pragma unroll
  for (int h = 0; h < 2; h++){
    const float4* X = (const float4*)(h ? xlr : xhr);
    _Float16* D = dst + (size_t)h*8388608;
#pragma unroll
    for (int k = 0; k < 4; k++){
      size_t f4 = (size_t)k*524288 + i;
      float4 v = X[f4];
      union { _Float16 h4[4]; unsigned long long u; } pk;
      pk.h4[0]=(_Float16)v.x; pk.h4[1]=(_Float16)v.y; pk.h4[2]=(_Float16)v.z; pk.h4[3]=(_Float16)v.w;
      *(unsigned long long*)(D + f4*4) = pk.u;
    }
  }
}

// ---------- numpy-exact T1[r] = (x_r**2).sum() (AVX512 twin) ----------
__global__ __launch_bounds__(256) void t1_np(const float* __restrict__ xhr, const float* __restrict__ xlr,
                                             char* __restrict__ ws){
  __shared__ float rowbuf[64][260];
  int b = blockIdx.x;
  int h = b >> 9;
  int r0 = (b & 511) * 64;
  const float* X = h ? xlr : xhr;
  int t = threadIdx.x;
#pragma unroll
  for (int p = 0; p < 16; p++){
    int idx = p*256 + t;
    int rr = idx >> 6, cc = idx & 63;
    float4 v = *(const float4*)(X + (size_t)(r0+rr)*256 + cc*4);
    rowbuf[rr][cc*4+0]=v.x; rowbuf[rr][cc*4+1]=v.y; rowbuf[rr][cc*4+2]=v.z; rowbuf[rr][cc*4+3]=v.w;
  }
  __syncthreads();
  if (t < 64){
    const float* a = &rowbuf[t][0];
    float blk[2];
#pragma unroll
    for (int p = 0; p < 2; p++){
      const float* ap = a + p*128;
      float s[16];
#pragma unroll
      for (int l = 0; l < 16; l++){
        float q0 = __fmul_rn(ap[l      ], ap[l      ]);
        float q1 = __fmul_rn(ap[l + 16 ], ap[l + 16 ]);
        float q2 = __fmul_rn(ap[l + 32 ], ap[l + 32 ]);
        float q3 = __fmul_rn(ap[l + 48 ], ap[l + 48 ]);
        float q4 = __fmul_rn(ap[l + 64 ], ap[l + 64 ]);
        float q5 = __fmul_rn(ap[l + 80 ], ap[l + 80 ]);
        float q6 = __fmul_rn(ap[l + 96 ], ap[l + 96 ]);
        float q7 = __fmul_rn(ap[l + 112], ap[l + 112]);
        s[l] = __fadd_rn(__fadd_rn(__fadd_rn(q0,q1), __fadd_rn(q2,q3)),
                         __fadd_rn(__fadd_rn(q4,q5), __fadd_rn(q6,q7)));
      }
      float u[8];
#pragma unroll
      for (int l = 0; l < 8; l++) u[l] = __fadd_rn(s[l], s[l+8]);
      float v[4];
#pragma unroll
      for (int l = 0; l < 4; l++) v[l] = __fadd_rn(u[l], u[l+4]);
      blk[p] = __fadd_rn(__fadd_rn(v[0], v[2]), __fadd_rn(v[1], v[3]));
    }
    ((float*)(ws + W_T1))[h*32768 + r0 + t] = __fadd_rn(blk[0], blk[1]);
  }
}

// ---------- numpy-exact T3[k] = (e**2).sum(0): strictly sequential ----------
__global__ __launch_bounds__(256) void t3_np(const float* __restrict__ e, char* __restrict__ ws){
  int k = blockIdx.x*256 + threadIdx.x;
  float v0 = e[k];
  float acc = __fmul_rn(v0, v0);
  for (int i = 1; i < 256; i++){
    float v = e[i*1024 + k];
    acc = __fadd_rn(acc, __fmul_rn(v, v));
  }
  ((float*)(ws + W_T3))[k] = acc;
}

// ---------- main GEMM: f16 dist staging + exact-f32 candidate lists (cap4/tile, ovf-safe) ----------
__global__ __launch_bounds__(512, 4) void gemm_dist(char* __restrict__ ws, float* __restrict__ out){
  // Bimg/f16-dtile [0,65536) | sx@65536 | se@66560 | f1t u32[256]@67072 | cnt u32[256]@68096 | list u64[256][4]@69120
  __shared__ __align__(16) char smem[77312];
  _Float16* Bimg = (_Float16*)smem;
  float* sx = (float*)(smem + 65536);
  float* se = (float*)(smem + 66560);
  unsigned* f1tu = (unsigned*)(smem + 67072);
  unsigned* cntL = (unsigned*)(smem + 68096);
  unsigned long long* listL = (unsigned long long*)(smem + 69120);

  int bid = blockIdx.x;
  int xcd = bid & 7, slot = bid >> 3;
  int ct = slot & 7;
  int panel = ((slot >> 3) << 3) + xcd;
  int lrow0 = (panel & 127) << 8;
  int col0 = ct << 7;
  int t = threadIdx.x, lane = t & 63, wid = t >> 6;
  int wm = wid >> 1, wn = wid & 1;
  int kg = lane >> 4, rl = lane & 15;

  const _Float16* Xf = (const _Float16*)(out + O_DIST_HR2)
                     + ((panel < 128) ? 0 : 8388608) + (size_t)lrow0*256;

  // --- B image staging (f16, 16B-unit XOR swizzle) + per-row scratch init ---
  const _Float16* Ef = (const _Float16*)(ws + W_EF16);
#pragma unroll
  for (int i = 0; i < 8; i++){
    int chunk = i*512 + t;
    int c = chunk >> 5, kc = chunk & 31;
    uint4 v = *(const uint4*)(Ef + (size_t)(col0 + c)*256 + kc*8);
    int off = c*512 + ((kc*16) ^ ((c & 7) << 4));
    *(uint4*)((char*)Bimg + off) = v;
  }
  if (t < 128) se[t] = ((const float*)(ws + W_SSE))[col0 + t];
  if (t < 256){
    sx[t] = ((const float*)(ws + W_T1))[((panel < 128) ? 0 : 32768) + lrow0 + t];
    f1tu[t] = 0xFFFFFFFFu;
    cntL[t] = 0u;
    listL[t*4+0] = ~0ull; listL[t*4+1] = ~0ull; listL[t*4+2] = ~0ull; listL[t*4+3] = ~0ull;
  }
  __syncthreads();

  f32x4 acc[4][4] = {};
#pragma unroll 2
  for (int kk = 0; kk < 8; kk++){
    half8 av[4], bv[4];
#pragma unroll
    for (int fm = 0; fm < 4; fm++){
      int row = wm*64 + fm*16 + rl;
      av[fm] = *(const half8*)(Xf + (size_t)row*256 + kk*32 + kg*8);
    }
#pragma unroll
    for (int fn = 0; fn < 4; fn++){
      int col = wn*64 + fn*16 + rl;
      bv[fn] = *(const half8*)((char*)Bimg + col*512 + ((kk*64 + kg*16) ^ ((col & 7) << 4)));
    }
#pragma unroll
    for (int fm = 0; fm < 4; fm++)
#pragma unroll
      for (int fn = 0; fn < 4; fn++)
        acc[fm][fn] = __builtin_amdgcn_mfma_f32_16x16x32_f16(av[fm], bv[fn], acc[fm][fn], 0, 0, 0);
  }
  __syncthreads();    // Bimg reads done; f16 tile overwrite safe

  // --- pass A: per-row tile min (exact f32 d) ---
  for (int fm = 0; fm < 4; fm++){
    float dmn[4] = {1e30f, 1e30f, 1e30f, 1e30f};
#pragma unroll
    for (int fn = 0; fn < 4; fn++){
      float sec = se[wn*64 + fn*16 + rl];
      f32x4 a = acc[fm][fn];
#pragma unroll
      for (int j = 0; j < 4; j++){
        int br = wm*64 + fm*16 + kg*4 + j;
        dmn[j] = fminf(dmn[j], fmaf(-2.f, a[j], sx[br] + sec));
      }
    }
#pragma unroll
    for (int m = 1; m < 16; m <<= 1)
#pragma unroll
      for (int j = 0; j < 4; j++)
        dmn[j] = fminf(dmn[j], __shfl_xor(dmn[j], m));
    if (rl == 0){
#pragma unroll
      for (int j = 0; j < 4; j++){
        int br = wm*64 + fm*16 + kg*4 + j;
        atomicMin(&f1tu[br], __float_as_uint(dmn[j]));   // d > 0 -> bit-monotone
      }
    }
  }
  __syncthreads();

  // --- pass B: f16 tile fill + exact-f32 candidate posting ---
  for (int fm = 0; fm < 4; fm++){
#pragma unroll
    for (int j = 0; j < 4; j++){
      int br = wm*64 + fm*16 + kg*4 + j;      // C/D layout: col=lane&15, row=(lane>>4)*4+reg
      float thrA = __uint_as_float(f1tu[br]) + MARGIN;
      float sxb = sx[br];
#pragma unroll
      for (int fn = 0; fn < 4; fn++){
        int col = wn*64 + fn*16 + rl;
        float d = fmaf(-2.f, acc[fm][fn][j], sxb + se[col]);
        *(_Float16*)(smem + br*256 + ((col*2) ^ ((br & 7) << 4))) = (_Float16)d;
        if (d <= thrA){
          unsigned idx = atomicAdd(&cntL[br], 1u);
          if (idx < 4u)
            listL[br*4 + idx] = ((unsigned long long)__float_as_uint(d) << 32) | (unsigned)(col0 + col);
        }
      }
    }
  }
  __syncthreads();

  // --- stream f16 tile (256 rows x 256B) to staging (ste region), 8B/lane nt ---
  size_t growbase = (size_t)(((panel < 128) ? 0 : 32768) + lrow0);
  char* stg = (char*)out;
#pragma unroll
  for (int it = 0; it < 16; it++){
    int idx = it*512 + t;
    int row = idx >> 5, c8 = idx & 31;
    unsigned long long v = *(const unsigned long long*)(smem + row*256 + ((c8*8) ^ ((row & 7) << 4)));
    __builtin_nontemporal_store(v,
      (unsigned long long*)(stg + (growbase + row)*2048 + col0*2 + c8*8));
  }

  // --- store candidate lists + counts into dist1 region (pre-expand scratch) ---
  if (t < 256){
    int rc = panel*256 + t;
    unsigned long long* KO = (unsigned long long*)(out + O_DIST_HR1);
    size_t kb = ((size_t)ct*65536 + (size_t)rc)*4;
    KO[kb+0] = listL[t*4+0]; KO[kb+1] = listL[t*4+1];
    KO[kb+2] = listL[t*4+2]; KO[kb+3] = listL[t*4+3];
    ((unsigned*)(out + O_DIST_HR1))[CNT_U32_OFF + ct*65536 + rc] = cntL[t];
  }
}

// ---------- merge candidate lists -> find + flags ----------
__global__ __launch_bounds__(256) void merge_flag(char* __restrict__ ws, const float* __restrict__ out){
  int rc = blockIdx.x*256 + threadIdx.x;
  const unsigned long long* K = (const unsigned long long*)(out + O_DIST_HR1);
  const unsigned* C = (const unsigned*)(out + O_DIST_HR1) + CNT_U32_OFF;
  unsigned long long a = ~0ull, b = ~0ull;
  bool ovf = false;
#pragma unroll
  for (int ct = 0; ct < 8; ct++){
    ovf = ovf || (C[(size_t)ct*65536 + rc] > 4u);
    size_t base = ((size_t)ct*65536 + (size_t)rc)*4;
#pragma unroll
    for (int q = 0; q < 4; q++) ins2(K[base+q], a, b);
  }
  ((int*)(ws + W_FIND))[rc] = (int)(unsigned)(a & 0xFFFFFFFFu);
  float f1 = __uint_as_float((unsigned)(a >> 32));
  float f2 = __uint_as_float((unsigned)(b >> 32));
  if (ovf || (f2 - f1 < MARGIN)){
    unsigned idx = atomicAdd((unsigned*)(ws + W_CNT), 1u);
    ((int*)(ws + W_FROWS))[idx] = rc | (ovf ? (int)0x80000000 : 0);
    ((float*)(ws + W_FMIN))[idx] = f1;
  }
}

// ---------- numpy-f32-exact re-decision: evaluate listed candidates (or full scan on ovf) ----------
__device__ __forceinline__ float exact_d(const float4* __restrict__ x4, const float* __restrict__ Et,
                                         float t1v, const float* __restrict__ T3, int k){
  const float4* e4 = (const float4*)(Et + (size_t)k*256);
  float c = 0.f;
  for (int i = 0; i < 64; i++){
    float4 xv = x4[i], ev = e4[i];
    c = fmaf(xv.x, ev.x, c);
    c = fmaf(xv.y, ev.y, c);
    c = fmaf(xv.z, ev.z, c);
    c = fmaf(xv.w, ev.w, c);
  }
  return __fadd_rn(__fsub_rn(t1v, __fmul_rn(2.f, c)), T3[k]);
}

__global__ __launch_bounds__(256) void refine_np(const float* __restrict__ xhr, const float* __restrict__ xlr,
                                                 char* __restrict__ ws, const float* __restrict__ out){
  unsigned nf = *(const unsigned*)(ws + W_CNT);
  int lane = threadIdx.x & 63;
  unsigned wgl = blockIdx.x*4 + (threadIdx.x >> 6);
  const float* Et = (const float*)(ws + W_ET);
  const float* T1 = (const float*)(ws + W_T1);
  const float* T3 = (const float*)(ws + W_T3);
  const int* rows = (const int*)(ws + W_FROWS);
  const float* fmn = (const float*)(ws + W_FMIN);
  int* find = (int*)(ws + W_FIND);
  const unsigned long long* K = (const unsigned long long*)(out + O_DIST_HR1);
  for (unsigned ii = wgl; ii < nf; ii += gridDim.x*4){
    int rcw = rows[ii];
    bool ovf = rcw < 0;
    int rc = rcw & 0x7FFFFFFF;
    int h = rc >> 15, r = rc & 32767;
    const float4* x4 = (const float4*)((h ? xlr : xhr) + (size_t)r*256);
    float t1v = T1[rc];
    unsigned long long bestkey = ~0ull;
    if (!ovf){
      if (lane < 32){
        unsigned long long kk = K[((size_t)(lane >> 2)*65536 + (size_t)rc)*4 + (lane & 3)];
        float dm = __uint_as_float((unsigned)(kk >> 32));
        if (dm <= fmn[ii] + MARGIN){                 // NaN padding fails
          int k = (int)(unsigned)(kk & 0xFFFFFFFFu);
          float d = exact_d(x4, Et, t1v, T3, k);
          bestkey = ((unsigned long long)__float_as_uint(d) << 32) | (unsigned)k;
        }
      }
    } else {
      for (int k = lane; k < 1024; k += 64){
        float d = exact_d(x4, Et, t1v, T3, k);
        unsigned long long key = ((unsigned long long)__float_as_uint(d) << 32) | (unsigned)k;
        if (key < bestkey) bestkey = key;
      }
    }
#pragma unroll
    for (int m2 = 1; m2 < 64; m2 <<= 1){
      unsigned long long o = __shfl_xor(bestkey, m2);
      if (o < bestkey) bestkey = o;
    }
    if (lane == 0) find[rc] = (int)(unsigned)(bestkey & 0xFFFFFFFFu);
  }
}

// ---------- expand: f16 staging -> f32 dist1 + dist2 (clean streaming writer) ----------
__global__ __launch_bounds__(256) void expand_dist(float* __restrict__ out){
  const unsigned long long* src = (const unsigned long long*)out;   // staging: 4 f16 per u64
  float* d1 = out + O_DIST_HR1;
  float* d2 = out + O_DIST_HR2;
  size_t i = (size_t)blockIdx.x*256 + threadIdx.x;
#pragma unroll
  for (int k = 0; k < 32; k++){
    size_t idx = (size_t)k*524288 + i;
    union { unsigned long long u; _Float16 h[4]; } pk;
    pk.u = src[idx];
    f32x4 q;
    q[0] = (float)pk.h[0]; q[1] = (float)pk.h[1]; q[2] = (float)pk.h[2]; q[3] = (float)pk.h[3];
    __builtin_nontemporal_store(q, (f32x4*)(d1 + idx*4));
    __builtin_nontemporal_store(q, (f32x4*)(d2 + idx*4));
  }
}

// ---------- gather q, write ste x2 + ind x2, accumulate diff ----------
__global__ __launch_bounds__(256) void finalize(const float* __restrict__ xhr, const float* __restrict__ xlr,
                                                char* __restrict__ ws, float* __restrict__ out){
  int b = blockIdx.x;
  int h = b >> 9, chunk = b & 511;
  const float* X = h ? xlr : xhr;
  int wid = threadIdx.x >> 6, lane = threadIdx.x & 63;
  const float* Et = (const float*)(ws + W_ET);
  const int* find = (const int*)(ws + W_FIND);
  int sb1 = h ? O_STE_LR1 : O_STE_HR1;
  int sb2 = h ? O_STE_LR2 : O_STE_HR2;
  int ib1 = h ? O_IND_LR1 : O_IND_HR1;
  int ib2 = h ? O_IND_LR2 : O_IND_HR2;
  double part = 0.0;
  for (int rr = wid; rr < 64; rr += 4){
    int r = chunk*64 + rr;
    int k = find[h*32768 + r];
    float4 q = *(const float4*)(Et + (size_t)k*256 + lane*4);
    float4 x = *(const float4*)(X + (size_t)r*256 + lane*4);
    *(float4*)(out + sb1 + r*256 + lane*4) = q;
    *(float4*)(out + sb2 + r*256 + lane*4) = q;
    if (lane == 0){ out[ib1 + r] = (float)k; out[ib2 + r] = (float)k; }
    double d0 = (double)q.x - x.x, d1 = (double)q.y - x.y;
    double d2 = (double)q.z - x.z, d3 = (double)q.w - x.w;
    part += d0*d0 + d1*d1 + d2*d2 + d3*d3;
  }
#pragma unroll
  for (int m = 1; m < 64; m <<= 1) part += __shfl_xor(part, m);
  __shared__ double wsum[4];
  if (lane == 0) wsum[wid] = part;
  __syncthreads();
  if (threadIdx.x == 0)
    atomicAdd((double*)(ws + W_DIFF) + h, wsum[0] + wsum[1] + wsum[2] + wsum[3]);
}

__global__ void fin_diff(const char* __restrict__ ws, float* __restrict__ out){
  if (threadIdx.x == 0 && blockIdx.x == 0){
    const double* d = (const double*)(ws + W_DIFF);
    float dh = (float)(d[0] / 8388608.0);
    float dl = (float)(d[1] / 8388608.0);
    out[O_DIFF+0] = dh; out[O_DIFF+1] = dl; out[O_DIFF+2] = dh; out[O_DIFF+3] = dl;
  }
}

extern "C" void kernel_launch(void* const* d_in, const int* in_sizes, int n_in,
                              void* d_out, int out_size, void* d_ws, size_t ws_size,
                              hipStream_t stream){
  const float* xhr = (const float*)d_in[0];
  const float* xlr = (const float*)d_in[1];
  const float* emb = (const float*)d_in[2];
  float* out = (float*)d_out;
  char* ws = (char*)d_ws;
  hipMemsetAsync(d_ws, 0, 8192, stream);
  prep<<<64, 256, 0, stream>>>(emb, ws);
  xf16_prep<<<2048, 256, 0, stream>>>(xhr, xlr, out);
  t1_np<<<1024, 256, 0, stream>>>(xhr, xlr, ws);
  t3_np<<<4, 256, 0, stream>>>(emb, ws);
  gemm_dist<<<2048, 512, 0, stream>>>(ws, out);
  merge_flag<<<256, 256, 0, stream>>>(ws, out);
  refine_np<<<1024, 256, 0, stream>>>(xhr, xlr, ws, out);
  expand_dist<<<2048, 256, 0, stream>>>(out);
  finalize<<<1024, 256, 0, stream>>>(xhr, xlr, ws, out);
  fin_diff<<<1, 64, 0, stream>>>(ws, out);
}

// Round 11
// 411.943 us; speedup vs baseline: 4.8386x; 3.8544x over previous
//
#include <hip/hip_runtime.h>
#include <stdint.h>

typedef _Float16 half8 __attribute__((ext_vector_type(8)));
typedef float f32x4 __attribute__((ext_vector_type(4)));

#define MARGIN 1e-3f

// ---- out element offsets (flattened tuple, return order) ----
#define O_STE_HR1 0
#define O_STE_LR1 8388608
#define O_STE_HR2 16777216
#define O_STE_LR2 25165824
#define O_DIFF    33554432
#define O_IND_HR1 33554436
#define O_IND_LR1 33587204
#define O_IND_HR2 33619972
#define O_IND_LR2 33652740
#define O_DIST_HR1 33685508
#define O_DIST_LR1 67239940
#define O_DIST_HR2 100794372
#define O_DIST_LR2 134348804

// key/cnt planes live in the dist1 region until expand_dist overwrites it
// keys: u64[(rc*8+ct)*4+q]  (row-major by rc -> one 256B span per row)
#define CNT_U32_OFF 4194304   // u32 offset past 2,097,152 u64 keys; cnt[rc*8+ct]

// ---- ws byte offsets ----
#define W_DIFF 0          // 2 x double
#define W_CNT  16         // u32 flagged count
#define W_SSE  4096       // f32[1024] sumsq_e (approx path)
#define W_EF16 8192       // _Float16 [1024 cols][256 k]  (512 KB)
#define W_ET   532480     // f32 [1024 cols][256 k]       (1 MB) exact transpose
#define W_FIND     7872512   // i32 [65536] final index
#define W_FROWS    8134656   // i32 [65536] flagged rows (bit31 = overflow)
#define W_FMIN     8396800   // f32 [65536] flagged row f1
#define W_T1       8658944   // f32 [65536] numpy-exact sum(x^2) per row
#define W_T3       8921088   // f32 [1024]  numpy-exact sum(e^2) per col

__device__ __forceinline__ void ins2(unsigned long long k, unsigned long long &a, unsigned long long &b){
  if (k < a){ b = a; a = k; } else if (k < b){ b = k; }
}

// ---------- prep: transpose embed -> Et (f32), Ef16 (f16), sumsq_e (approx) ----------
__global__ __launch_bounds__(256) void prep(const float* __restrict__ e, char* __restrict__ ws){
  __shared__ float tile[64][65];
  int t = threadIdx.x;
  int k0 = (blockIdx.x & 3) * 64;
  int c0 = (blockIdx.x >> 2) * 64;
  float* Et = (float*)(ws + W_ET);
  _Float16* Ef = (_Float16*)(ws + W_EF16);
  float* sse = (float*)(ws + W_SSE);
#pragma unroll
  for (int p = 0; p < 4; p++){
    int kr = p*16 + (t >> 4);
    int cc = (t & 15) * 4;
    float4 v = *(const float4*)(e + (k0 + kr)*1024 + c0 + cc);
    tile[kr][cc+0]=v.x; tile[kr][cc+1]=v.y; tile[kr][cc+2]=v.z; tile[kr][cc+3]=v.w;
  }
  __syncthreads();
#pragma unroll
  for (int p = 0; p < 4; p++){
    int cr = p*16 + (t >> 4);
    int kc = (t & 15) * 4;
    float4 v;
    v.x = tile[kc+0][cr]; v.y = tile[kc+1][cr]; v.z = tile[kc+2][cr]; v.w = tile[kc+3][cr];
    *(float4*)(Et + (c0+cr)*256 + k0 + kc) = v;
    union { _Float16 h[4]; unsigned long long u; } pk;
    pk.h[0]=(_Float16)v.x; pk.h[1]=(_Float16)v.y; pk.h[2]=(_Float16)v.z; pk.h[3]=(_Float16)v.w;
    *(unsigned long long*)(Ef + (c0+cr)*256 + k0 + kc) = pk.u;
  }
  if (t < 64){
    float s = 0.f;
    for (int k = 0; k < 64; k++){ float v = tile[k][t]; s += v*v; }
    atomicAdd(&sse[c0 + t], s);
  }
}

// ---------- Xf16: RTE f32->f16 image of both inputs, staged in dist2 region ----------
__global__ __launch_bounds__(256) void xf16_prep(const float* __restrict__ xhr, const float* __restrict__ xlr,
                                                 float* __restrict__ out){
  _Float16* dst = (_Float16*)(out + O_DIST_HR2);
  size_t i = (size_t)blockIdx.x*256 + threadIdx.x;   // float4 index
#pragma unroll
  for (int h = 0; h < 2; h++){
    const float4* X = (const float4*)(h ? xlr : xhr);
    _Float16* D = dst + (size_t)h*8388608;
#pragma unroll
    for (int k = 0; k < 4; k++){
      size_t f4 = (size_t)k*524288 + i;
      float4 v = X[f4];
      union { _Float16 h4[4]; unsigned long long u; } pk;
      pk.h4[0]=(_Float16)v.x; pk.h4[1]=(_Float16)v.y; pk.h4[2]=(_Float16)v.z; pk.h4[3]=(_Float16)v.w;
      *(unsigned long long*)(D + f4*4) = pk.u;
    }
  }
}

// ---------- numpy-exact T1[r] = (x_r**2).sum() (AVX512 twin) ----------
__global__ __launch_bounds__(256) void t1_np(const float* __restrict__ xhr, const float* __restrict__ xlr,
                                             char* __restrict__ ws){
  __shared__ float rowbuf[64][260];
  int b = blockIdx.x;
  int h = b >> 9;
  int r0 = (b & 511) * 64;
  const float* X = h ? xlr : xhr;
  int t = threadIdx.x;
#pragma unroll
  for (int p = 0; p < 16; p++){
    int idx = p*256 + t;
    int rr = idx >> 6, cc = idx & 63;
    float4 v = *(const float4*)(X + (size_t)(r0+rr)*256 + cc*4);
    rowbuf[rr][cc*4+0]=v.x; rowbuf[rr][cc*4+1]=v.y; rowbuf[rr][cc*4+2]=v.z; rowbuf[rr][cc*4+3]=v.w;
  }
  __syncthreads();
  if (t < 64){
    const float* a = &rowbuf[t][0];
    float blk[2];
#pragma unroll
    for (int p = 0; p < 2; p++){
      const float* ap = a + p*128;
      float s[16];
#pragma unroll
      for (int l = 0; l < 16; l++){
        float q0 = __fmul_rn(ap[l      ], ap[l      ]);
        float q1 = __fmul_rn(ap[l + 16 ], ap[l + 16 ]);
        float q2 = __fmul_rn(ap[l + 32 ], ap[l + 32 ]);
        float q3 = __fmul_rn(ap[l + 48 ], ap[l + 48 ]);
        float q4 = __fmul_rn(ap[l + 64 ], ap[l + 64 ]);
        float q5 = __fmul_rn(ap[l + 80 ], ap[l + 80 ]);
        float q6 = __fmul_rn(ap[l + 96 ], ap[l + 96 ]);
        float q7 = __fmul_rn(ap[l + 112], ap[l + 112]);
        s[l] = __fadd_rn(__fadd_rn(__fadd_rn(q0,q1), __fadd_rn(q2,q3)),
                         __fadd_rn(__fadd_rn(q4,q5), __fadd_rn(q6,q7)));
      }
      float u[8];
#pragma unroll
      for (int l = 0; l < 8; l++) u[l] = __fadd_rn(s[l], s[l+8]);
      float v[4];
#pragma unroll
      for (int l = 0; l < 4; l++) v[l] = __fadd_rn(u[l], u[l+4]);
      blk[p] = __fadd_rn(__fadd_rn(v[0], v[2]), __fadd_rn(v[1], v[3]));
    }
    ((float*)(ws + W_T1))[h*32768 + r0 + t] = __fadd_rn(blk[0], blk[1]);
  }
}

// ---------- numpy-exact T3[k] = (e**2).sum(0): strictly sequential ----------
__global__ __launch_bounds__(256) void t3_np(const float* __restrict__ e, char* __restrict__ ws){
  int k = blockIdx.x*256 + threadIdx.x;
  float v0 = e[k];
  float acc = __fmul_rn(v0, v0);
  for (int i = 1; i < 256; i++){
    float v = e[i*1024 + k];
    acc = __fadd_rn(acc, __fmul_rn(v, v));
  }
  ((float*)(ws + W_T3))[k] = acc;
}

// ---------- main GEMM: f16 dist staging + exact-f32 candidate lists (cap4/tile, ovf-safe) ----------
__global__ __launch_bounds__(512, 4) void gemm_dist(char* __restrict__ ws, float* __restrict__ out){
  // Bimg/f16-dtile [0,65536) | sx@65536 | se@66560 | f1t u32[256]@67072 | cnt u32[256]@68096 | list u64[256][4]@69120
  __shared__ __align__(16) char smem[77312];
  _Float16* Bimg = (_Float16*)smem;
  float* sx = (float*)(smem + 65536);
  float* se = (float*)(smem + 66560);
  unsigned* f1tu = (unsigned*)(smem + 67072);
  unsigned* cntL = (unsigned*)(smem + 68096);
  unsigned long long* listL = (unsigned long long*)(smem + 69120);

  int bid = blockIdx.x;
  int xcd = bid & 7, slot = bid >> 3;
  int ct = slot & 7;
  int panel = ((slot >> 3) << 3) + xcd;
  int lrow0 = (panel & 127) << 8;
  int col0 = ct << 7;
  int t = threadIdx.x, lane = t & 63, wid = t >> 6;
  int wm = wid >> 1, wn = wid & 1;
  int kg = lane >> 4, rl = lane & 15;

  const _Float16* Xf = (const _Float16*)(out + O_DIST_HR2)
                     + ((panel < 128) ? 0 : 8388608) + (size_t)lrow0*256;

  // --- B image staging (f16, 16B-unit XOR swizzle) + per-row scratch init ---
  const _Float16* Ef = (const _Float16*)(ws + W_EF16);
#pragma unroll
  for (int i = 0; i < 8; i++){
    int chunk = i*512 + t;
    int c = chunk >> 5, kc = chunk & 31;
    uint4 v = *(const uint4*)(Ef + (size_t)(col0 + c)*256 + kc*8);
    int off = c*512 + ((kc*16) ^ ((c & 7) << 4));
    *(uint4*)((char*)Bimg + off) = v;
  }
  if (t < 128) se[t] = ((const float*)(ws + W_SSE))[col0 + t];
  if (t < 256){
    sx[t] = ((const float*)(ws + W_T1))[((panel < 128) ? 0 : 32768) + lrow0 + t];
    f1tu[t] = 0xFFFFFFFFu;
    cntL[t] = 0u;
    listL[t*4+0] = ~0ull; listL[t*4+1] = ~0ull; listL[t*4+2] = ~0ull; listL[t*4+3] = ~0ull;
  }
  __syncthreads();

  f32x4 acc[4][4] = {};
#pragma unroll 2
  for (int kk = 0; kk < 8; kk++){
    half8 av[4], bv[4];
#pragma unroll
    for (int fm = 0; fm < 4; fm++){
      int row = wm*64 + fm*16 + rl;
      av[fm] = *(const half8*)(Xf + (size_t)row*256 + kk*32 + kg*8);
    }
#pragma unroll
    for (int fn = 0; fn < 4; fn++){
      int col = wn*64 + fn*16 + rl;
      bv[fn] = *(const half8*)((char*)Bimg + col*512 + ((kk*64 + kg*16) ^ ((col & 7) << 4)));
    }
#pragma unroll
    for (int fm = 0; fm < 4; fm++)
#pragma unroll
      for (int fn = 0; fn < 4; fn++)
        acc[fm][fn] = __builtin_amdgcn_mfma_f32_16x16x32_f16(av[fm], bv[fn], acc[fm][fn], 0, 0, 0);
  }
  __syncthreads();    // Bimg reads done; f16 tile overwrite safe

  // --- pass A: per-row tile min (exact f32 d) ---
  for (int fm = 0; fm < 4; fm++){
    float dmn[4] = {1e30f, 1e30f, 1e30f, 1e30f};
#pragma unroll
    for (int fn = 0; fn < 4; fn++){
      float sec = se[wn*64 + fn*16 + rl];
      f32x4 a = acc[fm][fn];
#pragma unroll
      for (int j = 0; j < 4; j++){
        int br = wm*64 + fm*16 + kg*4 + j;
        dmn[j] = fminf(dmn[j], fmaf(-2.f, a[j], sx[br] + sec));
      }
    }
#pragma unroll
    for (int m = 1; m < 16; m <<= 1)
#pragma unroll
      for (int j = 0; j < 4; j++)
        dmn[j] = fminf(dmn[j], __shfl_xor(dmn[j], m));
    if (rl == 0){
#pragma unroll
      for (int j = 0; j < 4; j++){
        int br = wm*64 + fm*16 + kg*4 + j;
        atomicMin(&f1tu[br], __float_as_uint(dmn[j]));   // d > 0 -> bit-monotone
      }
    }
  }
  __syncthreads();

  // --- pass B: f16 tile fill + exact-f32 candidate posting ---
  for (int fm = 0; fm < 4; fm++){
#pragma unroll
    for (int j = 0; j < 4; j++){
      int br = wm*64 + fm*16 + kg*4 + j;      // C/D layout: col=lane&15, row=(lane>>4)*4+reg
      float thrA = __uint_as_float(f1tu[br]) + MARGIN;
      float sxb = sx[br];
#pragma unroll
      for (int fn = 0; fn < 4; fn++){
        int col = wn*64 + fn*16 + rl;
        float d = fmaf(-2.f, acc[fm][fn][j], sxb + se[col]);
        *(_Float16*)(smem + br*256 + ((col*2) ^ ((br & 7) << 4))) = (_Float16)d;
        if (d <= thrA){
          unsigned idx = atomicAdd(&cntL[br], 1u);
          if (idx < 4u)
            listL[br*4 + idx] = ((unsigned long long)__float_as_uint(d) << 32) | (unsigned)(col0 + col);
        }
      }
    }
  }
  __syncthreads();

  // --- stream f16 tile (256 rows x 256B) to staging (ste region), 8B/lane nt ---
  size_t growbase = (size_t)(((panel < 128) ? 0 : 32768) + lrow0);
  char* stg = (char*)out;
#pragma unroll
  for (int it = 0; it < 16; it++){
    int idx = it*512 + t;
    int row = idx >> 5, c8 = idx & 31;
    unsigned long long v = *(const unsigned long long*)(smem + row*256 + ((c8*8) ^ ((row & 7) << 4)));
    __builtin_nontemporal_store(v,
      (unsigned long long*)(stg + (growbase + row)*2048 + col0*2 + c8*8));
  }

  // --- store candidate lists + counts, ROW-MAJOR by rc (contiguous 256B+32B per row) ---
  if (t < 256){
    int rc = panel*256 + t;
    unsigned long long* KO = (unsigned long long*)(out + O_DIST_HR1);
    size_t kb = ((size_t)rc*8 + (size_t)ct)*4;
    KO[kb+0] = listL[t*4+0]; KO[kb+1] = listL[t*4+1];
    KO[kb+2] = listL[t*4+2]; KO[kb+3] = listL[t*4+3];
    ((unsigned*)(out + O_DIST_HR1))[CNT_U32_OFF + rc*8 + ct] = cntL[t];
  }
}

// ---------- merge candidate lists -> find + flags ----------
__global__ __launch_bounds__(256) void merge_flag(char* __restrict__ ws, const float* __restrict__ out){
  int rc = blockIdx.x*256 + threadIdx.x;
  const unsigned long long* K = (const unsigned long long*)(out + O_DIST_HR1);
  const unsigned* C = (const unsigned*)(out + O_DIST_HR1) + CNT_U32_OFF;
  unsigned long long a = ~0ull, b = ~0ull;
  bool ovf = false;
#pragma unroll
  for (int ct = 0; ct < 8; ct++){
    ovf = ovf || (C[(size_t)rc*8 + ct] > 4u);
    size_t base = ((size_t)rc*8 + (size_t)ct)*4;
#pragma unroll
    for (int q = 0; q < 4; q++) ins2(K[base+q], a, b);
  }
  ((int*)(ws + W_FIND))[rc] = (int)(unsigned)(a & 0xFFFFFFFFu);
  float f1 = __uint_as_float((unsigned)(a >> 32));
  float f2 = __uint_as_float((unsigned)(b >> 32));
  if (ovf || (f2 - f1 < MARGIN)){
    unsigned idx = atomicAdd((unsigned*)(ws + W_CNT), 1u);
    ((int*)(ws + W_FROWS))[idx] = rc | (ovf ? (int)0x80000000 : 0);
    ((float*)(ws + W_FMIN))[idx] = f1;
  }
}

// ---------- numpy-f32-exact re-decision: evaluate listed candidates (or full scan on ovf) ----------
__device__ __forceinline__ float exact_d(const float4* __restrict__ x4, const float* __restrict__ Et,
                                         float t1v, const float* __restrict__ T3, int k){
  const float4* e4 = (const float4*)(Et + (size_t)k*256);
  float c = 0.f;
  for (int i = 0; i < 64; i++){
    float4 xv = x4[i], ev = e4[i];
    c = fmaf(xv.x, ev.x, c);
    c = fmaf(xv.y, ev.y, c);
    c = fmaf(xv.z, ev.z, c);
    c = fmaf(xv.w, ev.w, c);
  }
  return __fadd_rn(__fsub_rn(t1v, __fmul_rn(2.f, c)), T3[k]);
}

__global__ __launch_bounds__(256) void refine_np(const float* __restrict__ xhr, const float* __restrict__ xlr,
                                                 char* __restrict__ ws, const float* __restrict__ out){
  unsigned nf = *(const unsigned*)(ws + W_CNT);
  int lane = threadIdx.x & 63;
  unsigned wgl = blockIdx.x*4 + (threadIdx.x >> 6);
  const float* Et = (const float*)(ws + W_ET);
  const float* T1 = (const float*)(ws + W_T1);
  const float* T3 = (const float*)(ws + W_T3);
  const int* rows = (const int*)(ws + W_FROWS);
  const float* fmn = (const float*)(ws + W_FMIN);
  int* find = (int*)(ws + W_FIND);
  const unsigned long long* K = (const unsigned long long*)(out + O_DIST_HR1);
  for (unsigned ii = wgl; ii < nf; ii += gridDim.x*4){
    int rcw = rows[ii];
    bool ovf = rcw < 0;
    int rc = rcw & 0x7FFFFFFF;
    int h = rc >> 15, r = rc & 32767;
    const float4* x4 = (const float4*)((h ? xlr : xhr) + (size_t)r*256);
    float t1v = T1[rc];
    unsigned long long bestkey = ~0ull;
    if (!ovf){
      if (lane < 32){
        unsigned long long kk = K[(size_t)rc*32 + lane];   // contiguous 256B per row
        float dm = __uint_as_float((unsigned)(kk >> 32));
        if (dm <= fmn[ii] + MARGIN){                 // NaN padding fails
          int k = (int)(unsigned)(kk & 0xFFFFFFFFu);
          float d = exact_d(x4, Et, t1v, T3, k);
          bestkey = ((unsigned long long)__float_as_uint(d) << 32) | (unsigned)k;
        }
      }
    } else {
      for (int k = lane; k < 1024; k += 64){
        float d = exact_d(x4, Et, t1v, T3, k);
        unsigned long long key = ((unsigned long long)__float_as_uint(d) << 32) | (unsigned)k;
        if (key < bestkey) bestkey = key;
      }
    }
#pragma unroll
    for (int m2 = 1; m2 < 64; m2 <<= 1){
      unsigned long long o = __shfl_xor(bestkey, m2);
      if (o < bestkey) bestkey = o;
    }
    if (lane == 0) find[rc] = (int)(unsigned)(bestkey & 0xFFFFFFFFu);
  }
}

// ---------- expand: f16 staging -> f32 dist1 + dist2 (clean streaming writer) ----------
__global__ __launch_bounds__(256) void expand_dist(float* __restrict__ out){
  const unsigned long long* src = (const unsigned long long*)out;   // staging: 4 f16 per u64
  float* d1 = out + O_DIST_HR1;
  float* d2 = out + O_DIST_HR2;
  size_t i = (size_t)blockIdx.x*256 + threadIdx.x;
#pragma unroll
  for (int k = 0; k < 32; k++){
    size_t idx = (size_t)k*524288 + i;
    union { unsigned long long u; _Float16 h[4]; } pk;
    pk.u = src[idx];
    f32x4 q;
    q[0] = (float)pk.h[0]; q[1] = (float)pk.h[1]; q[2] = (float)pk.h[2]; q[3] = (float)pk.h[3];
    __builtin_nontemporal_store(q, (f32x4*)(d1 + idx*4));
    __builtin_nontemporal_store(q, (f32x4*)(d2 + idx*4));
  }
}

// ---------- gather q, write ste x2 + ind x2, accumulate diff ----------
__global__ __launch_bounds__(256) void finalize(const float* __restrict__ xhr, const float* __restrict__ xlr,
                                                char* __restrict__ ws, float* __restrict__ out){
  int b = blockIdx.x;
  int h = b >> 9, chunk = b & 511;
  const float* X = h ? xlr : xhr;
  int wid = threadIdx.x >> 6, lane = threadIdx.x & 63;
  const float* Et = (const float*)(ws + W_ET);
  const int* find = (const int*)(ws + W_FIND);
  int sb1 = h ? O_STE_LR1 : O_STE_HR1;
  int sb2 = h ? O_STE_LR2 : O_STE_HR2;
  int ib1 = h ? O_IND_LR1 : O_IND_HR1;
  int ib2 = h ? O_IND_LR2 : O_IND_HR2;
  double part = 0.0;
  for (int rr = wid; rr < 64; rr += 4){
    int r = chunk*64 + rr;
    int k = find[h*32768 + r];
    float4 q = *(const float4*)(Et + (size_t)k*256 + lane*4);
    float4 x = *(const float4*)(X + (size_t)r*256 + lane*4);
    *(float4*)(out + sb1 + r*256 + lane*4) = q;
    *(float4*)(out + sb2 + r*256 + lane*4) = q;
    if (lane == 0){ out[ib1 + r] = (float)k; out[ib2 + r] = (float)k; }
    double d0 = (double)q.x - x.x, d1 = (double)q.y - x.y;
    double d2 = (double)q.z - x.z, d3 = (double)q.w - x.w;
    part += d0*d0 + d1*d1 + d2*d2 + d3*d3;
  }
#pragma unroll
  for (int m = 1; m < 64; m <<= 1) part += __shfl_xor(part, m);
  __shared__ double wsum[4];
  if (lane == 0) wsum[wid] = part;
  __syncthreads();
  if (threadIdx.x == 0)
    atomicAdd((double*)(ws + W_DIFF) + h, wsum[0] + wsum[1] + wsum[2] + wsum[3]);
}

__global__ void fin_diff(const char* __restrict__ ws, float* __restrict__ out){
  if (threadIdx.x == 0 && blockIdx.x == 0){
    const double* d = (const double*)(ws + W_DIFF);
    float dh = (float)(d[0] / 8388608.0);
    float dl = (float)(d[1] / 8388608.0);
    out[O_DIFF+0] = dh; out[O_DIFF+1] = dl; out[O_DIFF+2] = dh; out[O_DIFF+3] = dl;
  }
}

extern "C" void kernel_launch(void* const* d_in, const int* in_sizes, int n_in,
                              void* d_out, int out_size, void* d_ws, size_t ws_size,
                              hipStream_t stream){
  const float* xhr = (const float*)d_in[0];
  const float* xlr = (const float*)d_in[1];
  const float* emb = (const float*)d_in[2];
  float* out = (float*)d_out;
  char* ws = (char*)d_ws;
  hipMemsetAsync(d_ws, 0, 8192, stream);
  prep<<<64, 256, 0, stream>>>(emb, ws);
  xf16_prep<<<2048, 256, 0, stream>>>(xhr, xlr, out);
  t1_np<<<1024, 256, 0, stream>>>(xhr, xlr, ws);
  t3_np<<<4, 256, 0, stream>>>(emb, ws);
  gemm_dist<<<2048, 512, 0, stream>>>(ws, out);
  merge_flag<<<256, 256, 0, stream>>>(ws, out);
  refine_np<<<2048, 256, 0, stream>>>(xhr, xlr, ws, out);
  expand_dist<<<2048, 256, 0, stream>>>(out);
  finalize<<<1024, 256, 0, stream>>>(xhr, xlr, ws, out);
  fin_diff<<<1, 64, 0, stream>>>(ws, out);
}